// Round 10
// baseline (71.031 us; speedup 1.0000x reference)
//
#include <hip/hip_runtime.h>

#define Bsz 64
#define Ssz 512
#define Hsz 768
#define Tsz 9
#define NCH 16
#define LOG2E 1.4426950408889634f
#define LN2F  0.6931471805599453f
#define PSTR 17

__device__ __forceinline__ int SK(int s) { return s * Tsz + ((s >> 5) << 1); }

// ============ K1: fused emissions GEMM (P=2) + in-block chunk scans ============
// grid = B*NCH = 1024 blocks x 256 threads. Block (b,c):
//  phase G: computes em rows [c*32, c*32+32) (2 k-phases, 16 lanes/row) ->
//           global em AND LDS em_w; row 32 recomputed bit-identically (r5 trick).
//  phase S: waves 0-2 run 18 chunk-scan tasks (9 LSE + 9 Viterbi max-plus rows,
//           9 lanes/task, col-parallel shuffles) straight from LDS.
__global__ __launch_bounds__(256, 1) void emscan2_kernel(
    const float* __restrict__ x, const float* __restrict__ fcw,
    const float* __restrict__ fcb, const int* __restrict__ mask,
    const float* __restrict__ trans, float* __restrict__ em,
    float* __restrict__ R2, float* __restrict__ MV, int* __restrict__ cnt) {
    __shared__ __align__(16) float4 w4[Tsz * Hsz / 4];   // 27648 B
    __shared__ float bias[Tsz];
    __shared__ float part[16 * Tsz * PSTR];              // 9792 B
    __shared__ float em_w[33 * Tsz];                     // 1188 B
    __shared__ int   mk_w[33];
    __shared__ float Elds[81];
    __shared__ float Tlds[81];

    const int tid = threadIdx.x;
    const int bc = blockIdx.x;
    const int b = bc >> 4, c = bc & 15;
    const int base = c * 32;
    const size_t pos0 = (size_t)bc * 32;                 // = b*512 + c*32

    if (bc == 0 && tid == 0) *cnt = 0;                   // vit3's reduce counter

    const float4* fw4 = reinterpret_cast<const float4*>(fcw);
#pragma unroll
    for (int i = 0; i < 7; ++i) {
        const int o = tid + i * 256;
        if (o < 1728) w4[o] = fw4[o];
    }
    if (tid < Tsz) bias[tid] = fcb[tid];
    if (tid >= 16 && tid < 16 + 81) {
        const float t = trans[tid - 16];
        Tlds[tid - 16] = t;
        Elds[tid - 16] = exp2f(t * LOG2E);
    }
    if (tid >= 128 && tid < 128 + 33) {
        const int s = base + (tid - 128);
        mk_w[tid - 128] = (s < Ssz) ? mask[b * Ssz + s] : 0;
    }
    __syncthreads();

    const int p = tid >> 4, l = tid & 15;
    // ---- phase G: rows 0..31 (identical arithmetic to r9 emis) ----
    {
        const float4* xr0 = reinterpret_cast<const float4*>(x + (pos0 + p) * Hsz);
        const float4* xr1 = reinterpret_cast<const float4*>(x + (pos0 + 16 + p) * Hsz);
        float acc[Tsz][2];
#pragma unroll
        for (int t = 0; t < Tsz; ++t) { acc[t][0] = 0.0f; acc[t][1] = 0.0f; }
#pragma unroll 4
        for (int i = 0; i < 12; ++i) {
            const float4 xv0 = xr0[i * 16 + l];
            const float4 xv1 = xr1[i * 16 + l];
#pragma unroll
            for (int t = 0; t < Tsz; ++t) {
                const float4 wv = w4[t * 192 + i * 16 + l];
                acc[t][0] = fmaf(xv0.x, wv.x, fmaf(xv0.y, wv.y,
                            fmaf(xv0.z, wv.z, fmaf(xv0.w, wv.w, acc[t][0]))));
                acc[t][1] = fmaf(xv1.x, wv.x, fmaf(xv1.y, wv.y,
                            fmaf(xv1.z, wv.z, fmaf(xv1.w, wv.w, acc[t][1]))));
            }
        }
#pragma unroll
        for (int k = 0; k < 2; ++k) {                    // k compile-time
            __syncthreads();
#pragma unroll
            for (int t = 0; t < Tsz; ++t) part[(p * Tsz + t) * PSTR + l] = acc[t][k];
            __syncthreads();
            if (tid < 16 * Tsz) {
                const int pq = tid / Tsz, t = tid - pq * Tsz;
                float s = bias[t];
#pragma unroll
                for (int l2 = 0; l2 < 16; ++l2) s += part[(pq * Tsz + t) * PSTR + l2];
                em[(pos0 + (size_t)k * 16 + pq) * Tsz + t] = s;
                em_w[(k * 16 + pq) * Tsz + t] = s;
            }
        }
    }
    // ---- phase G2: row 32 (bit-identical to block (b,c+1)'s row 0) ----
    if (c < 15) {
        float acc2[Tsz];
#pragma unroll
        for (int t = 0; t < Tsz; ++t) acc2[t] = 0.0f;
        if (tid < 16) {
            const float4* xr2 = reinterpret_cast<const float4*>(x + (pos0 + 32) * Hsz);
#pragma unroll 4
            for (int i = 0; i < 12; ++i) {
                const float4 xv = xr2[i * 16 + l];
#pragma unroll
                for (int t = 0; t < Tsz; ++t) {
                    const float4 wv = w4[t * 192 + i * 16 + l];
                    acc2[t] = fmaf(xv.x, wv.x, fmaf(xv.y, wv.y,
                              fmaf(xv.z, wv.z, fmaf(xv.w, wv.w, acc2[t]))));
                }
            }
        }
        __syncthreads();
        if (tid < 16) {
#pragma unroll
            for (int t = 0; t < Tsz; ++t) part[t * PSTR + l] = acc2[t];
        }
        __syncthreads();
        if (tid < Tsz) {
            float s = bias[tid];
#pragma unroll
            for (int l2 = 0; l2 < 16; ++l2) s += part[tid * PSTR + l2];
            em_w[32 * Tsz + tid] = s;
        }
    }
    __syncthreads();

    // ---- phase S: 18 scan tasks on waves 0-2 (no barriers past this point) ----
    const int wv = tid >> 6, ln = tid & 63;
    const int q = ln / 9;                    // 0..6 valid (ln==63 idle)
    const int j = ln - q * 9;
    const int tsk = wv * 7 + q;
    if (wv >= 3 || q >= 7 || tsk >= 18) return;
    const int lb = 9 * q;
    const int ns = (c == 15) ? 31 : 32;      // steps = rows 1..ns

    if (tsk < 9) {
        // ---- LSE row a=tsk, probability domain (verbatim r8/r9 scan) ----
        const int a = tsk;
        float Ecol[Tsz];
#pragma unroll
        for (int i = 0; i < Tsz; ++i) Ecol[i] = Elds[i * Tsz + j];
        float pp = (j == a) ? 1.0f : 0.0f;
        float K = 0.0f;
        for (int r = 1; r <= ns; ++r) {
            float g = __shfl(pp, lb, 64) * Ecol[0];
#pragma unroll
            for (int i = 1; i < Tsz; ++i)
                g = fmaf(__shfl(pp, lb + i, 64), Ecol[i], g);
            const float np = g * exp2f(em_w[r * Tsz + j] * LOG2E);
            if (mk_w[r] > 0) pp = np;
            if (((r - 1) & 7) == 7) {
                float ss = __shfl(pp, lb, 64);
#pragma unroll
                for (int i = 1; i < Tsz; ++i) ss += __shfl(pp, lb + i, 64);
                K += __log2f(ss);
                const float inv = 1.0f / ss;
                pp *= inv;
            }
        }
        R2[((size_t)bc * Tsz + a) * Tsz + j] = K + __log2f(pp);
    } else {
        // ---- Viterbi max-plus row a=tsk-9 (verbatim r8/r9 scan) ----
        const int a = tsk - 9;
        float Tcol[Tsz];
#pragma unroll
        for (int i = 0; i < Tsz; ++i) Tcol[i] = Tlds[i * Tsz + j];
        float pp = (j == a) ? 0.0f : -1e30f;
        for (int r = 1; r <= ns; ++r) {
            float g = __shfl(pp, lb, 64) + Tcol[0];
#pragma unroll
            for (int i = 1; i < Tsz; ++i)
                g = fmaxf(g, __shfl(pp, lb + i, 64) + Tcol[i]);
            if (mk_w[r] > 0) pp = g + em_w[r * Tsz + j];
        }
        MV[(size_t)bc * 81 + a * Tsz + j] = pp;
    }
}

// first-max argmax of 9 values (strict > keeps FIRST max)
__device__ __forceinline__ void amax9(const float (&v)[Tsz], float& bv, int& bi) {
    float w01v = (v[1] > v[0]) ? v[1] : v[0]; int w01i = (v[1] > v[0]) ? 1 : 0;
    float w23v = (v[3] > v[2]) ? v[3] : v[2]; int w23i = (v[3] > v[2]) ? 3 : 2;
    float w45v = (v[5] > v[4]) ? v[5] : v[4]; int w45i = (v[5] > v[4]) ? 5 : 4;
    float w67v = (v[7] > v[6]) ? v[7] : v[6]; int w67i = (v[7] > v[6]) ? 7 : 6;
    float x03v = (w23v > w01v) ? w23v : w01v; int x03i = (w23v > w01v) ? w23i : w01i;
    float x47v = (w67v > w45v) ? w67v : w45v; int x47i = (w67v > w45v) ? w67i : w45i;
    float y07v = (x47v > x03v) ? x47v : x03v; int y07i = (x47v > x03v) ? x47i : x03i;
    bv = (v[8] > y07v) ? v[8] : y07v;
    bi = (v[8] > y07v) ? 8 : y07i;
}

// ============ K2: per-batch finish + fused final reduce (last block) ============
__global__ __launch_bounds__(192, 1) void vit3_kernel(
    const float* __restrict__ em, const int* __restrict__ labels,
    const int* __restrict__ mask, const int* __restrict__ lengths,
    const float* __restrict__ start_t, const float* __restrict__ end_t,
    const float* __restrict__ trans, const float* __restrict__ R2,
    const float* __restrict__ MV, float* __restrict__ out_path,
    float* __restrict__ ll, float* __restrict__ dout, int* __restrict__ cnt) {
    __shared__ __align__(16) float em_s[4640];          // skewed [s][j]
    __shared__ __align__(16) int   mk_s[Ssz];
    __shared__ __align__(16) float mv_s[NCH * 81];
    __shared__ __align__(16) float r2_s[NCH * 81];
    __shared__ float tr_s[81];
    __shared__ float st_s[12], en_s[12];
    __shared__ __align__(16) float alc[2][NCH][12];
    __shared__ float a2c[2][12];
    __shared__ unsigned char bp[(Ssz - 1) * Tsz];
    __shared__ unsigned char mapA[64][12], mapB[64][12];
    __shared__ float den_sh, num_sh;
    __shared__ int lastf;

    const int b = blockIdx.x, tid = threadIdx.x;
    const int wv = tid >> 6, ln = tid & 63;
    const int c = tid / 12, j9 = tid % 12;
    const float* emb = em + (size_t)b * Ssz * Tsz;
    const int* mkb = mask + b * Ssz;
    const int* lbb = labels + b * Ssz;

    for (int i = tid; i < Ssz * Tsz; i += 192) {
        const int s = i / 9, j = i - s * 9;
        em_s[SK(s) + j] = emb[i];
    }
    for (int i = tid; i < Ssz; i += 192) mk_s[i] = mkb[i];
    {
        const float4* v4 = reinterpret_cast<const float4*>(MV + (size_t)b * NCH * 81);
        float4* vd = reinterpret_cast<float4*>(mv_s);
        for (int i = tid; i < NCH * 81 / 4; i += 192) vd[i] = v4[i];
        const float4* r4 = reinterpret_cast<const float4*>(R2 + (size_t)b * NCH * 81);
        float4* rd = reinterpret_cast<float4*>(r2_s);
        for (int i = tid; i < NCH * 81 / 4; i += 192) rd[i] = r4[i];
        if (tid < 81) tr_s[tid] = trans[tid];
        if (tid >= 96 && tid < 96 + Tsz) {
            st_s[tid - 96] = start_t[tid - 96];
            en_s[tid - 96] = end_t[tid - 96];
        }
    }
    __syncthreads();

    float tc[Tsz];
    const int jj = (j9 < Tsz) ? j9 : Tsz - 1;
#pragma unroll
    for (int i = 0; i < Tsz; ++i) tc[i] = tr_s[i * Tsz + jj];

    float aj = 0.0f;
    if (c == 0 && j9 < Tsz) {
        aj = st_s[j9] + em_s[j9];
        alc[0][0][j9] = aj;
    }
    if (wv == 1 && ln < Tsz) a2c[0][ln] = (st_s[ln] + em_s[ln]) * LOG2E;

    for (int r = 0; r < NCH; ++r) {
        __syncthreads();
        if (r < NCH - 1 && c == r + 1 && j9 < Tsz) {
            const float* M = &mv_s[r * 81];
            float m = alc[0][r][0] + M[j9];
#pragma unroll
            for (int i = 1; i < Tsz; ++i)
                m = fmaxf(m, alc[0][r][i] + M[i * Tsz + j9]);
            aj = m;
            alc[0][c][j9] = m;
        }
        if (wv == 1 && ln < Tsz) {
            const float* Rr = &r2_s[r * 81];
            float xi[Tsz];
#pragma unroll
            for (int i = 0; i < Tsz; ++i) xi[i] = a2c[r & 1][i] + Rr[i * Tsz + ln];
            float m = xi[0];
#pragma unroll
            for (int i = 1; i < Tsz; ++i) m = fmaxf(m, xi[i]);
            float sm = 0.0f;
#pragma unroll
            for (int i = 0; i < Tsz; ++i) sm += exp2f(xi[i] - m);
            a2c[(r + 1) & 1][ln] = m + __log2f(sm);
        }
    }

    int pb = 0;
    for (int k = 0; k < 32; ++k) {
        __syncthreads();
        const int s = c * 32 + 1 + k;
        if (j9 < Tsz && s <= Ssz - 1) {
            const int mk = mk_s[s];
            float av[12];
            const float4* ap = reinterpret_cast<const float4*>(&alc[pb][c][0]);
            *reinterpret_cast<float4*>(&av[0]) = ap[0];
            *reinterpret_cast<float4*>(&av[4]) = ap[1];
            *reinterpret_cast<float4*>(&av[8]) = ap[2];
            float v[Tsz];
#pragma unroll
            for (int i = 0; i < Tsz; ++i) v[i] = av[i] + tc[i];
            float bv; int bi;
            amax9(v, bv, bi);
            bp[(s - 1) * Tsz + j9] = (unsigned char)((mk > 0) ? bi : j9);
            if (mk > 0) aj = bv + em_s[SK(s) + j9];
        }
        if (j9 < Tsz) alc[1 - pb][c][j9] = aj;
        pb ^= 1;
    }
    __syncthreads();

    float bb = alc[0][NCH - 1][0] + en_s[0];
    int last = 0;
#pragma unroll
    for (int q = 1; q < Tsz; ++q) {
        const float qq = alc[0][NCH - 1][q] + en_s[q];
        if (qq > bb) { bb = qq; last = q; }
    }

    const int lo = ln * 8;
    const int hi = min(lo + 7, Ssz - 2);
    if (wv == 0) {
        int xf[Tsz];
#pragma unroll
        for (int t = 0; t < Tsz; ++t) xf[t] = t;
        for (int k = hi; k >= lo; --k) {
#pragma unroll
            for (int t = 0; t < Tsz; ++t) xf[t] = bp[k * Tsz + xf[t]];
        }
#pragma unroll
        for (int t = 0; t < Tsz; ++t) mapA[ln][t] = (unsigned char)xf[t];
    } else if (wv == 1) {
        if (ln == 0) {
            float xv[Tsz];
#pragma unroll
            for (int i = 0; i < Tsz; ++i) xv[i] = a2c[0][i] + en_s[i] * LOG2E;
            float m = xv[0];
#pragma unroll
            for (int i = 1; i < Tsz; ++i) m = fmaxf(m, xv[i]);
            float sm = 0.0f;
#pragma unroll
            for (int i = 0; i < Tsz; ++i) sm += exp2f(xv[i] - m);
            den_sh = m + __log2f(sm);
        }
    } else {
        float part = 0.0f;
        for (int s = 1 + ln; s < Ssz; s += 64) {
            if (mk_s[s] > 0) {
                const int tg = lbb[s];
                int pq = s - 1;
                while (pq > 0 && mk_s[pq] == 0) --pq;
                part += tr_s[lbb[pq] * Tsz + tg] + em_s[SK(s) + tg];
            }
        }
#pragma unroll
        for (int off = 32; off >= 1; off >>= 1) part += __shfl_xor(part, off, 64);
        if (ln == 0) {
            const int tg0 = lbb[0];
            float num = part + st_s[tg0] + em_s[tg0];
            int pq = Ssz - 1;
            while (pq > 0 && mk_s[pq] == 0) --pq;
            num += en_s[lbb[pq]];
            num_sh = num;
        }
    }

#define VIT_RND(CUR, NXT, D)                                               \
    {                                                                      \
        unsigned char nn[Tsz];                                             \
        if (wv == 0) {                                                     \
            const int o = ln + (D);                                        \
            if (o < 64) {                                                  \
                _Pragma("unroll") for (int t = 0; t < Tsz; ++t)            \
                    nn[t] = CUR[ln][CUR[o][t]];                            \
            } else {                                                       \
                _Pragma("unroll") for (int t = 0; t < Tsz; ++t)            \
                    nn[t] = CUR[ln][t];                                    \
            }                                                              \
        }                                                                  \
        __syncthreads();                                                   \
        if (wv == 0) {                                                     \
            _Pragma("unroll") for (int t = 0; t < Tsz; ++t)                \
                NXT[ln][t] = nn[t];                                        \
        }                                                                  \
        __syncthreads();                                                   \
    }
    VIT_RND(mapA, mapB, 1)
    VIT_RND(mapB, mapA, 2)
    VIT_RND(mapA, mapB, 4)
    VIT_RND(mapB, mapA, 8)
    VIT_RND(mapA, mapB, 16)
    VIT_RND(mapB, mapA, 32)
#undef VIT_RND

    if (wv == 0) {
        int t = (ln == 63) ? last : (int)mapA[ln + 1][last];
        float* op = out_path + (size_t)b * Ssz;
        for (int k = hi; k >= lo; --k) {
            t = bp[k * Tsz + t];
            op[k] = (float)t;
        }
        if (ln == 0) op[Ssz - 1] = (float)last;
    }
    if (b == 0 && wv == 2) dout[1 + Bsz * Ssz + ln] = (float)lengths[ln];

    if (tid == 0) {
        ll[b] = num_sh - den_sh * LN2F;
        __threadfence();
        lastf = (atomicAdd(cnt, 1) == Bsz - 1) ? 1 : 0;
    }
    __syncthreads();
    if (lastf && wv == 0) {
        __threadfence();
        float v = ll[ln];
#pragma unroll
        for (int off = 32; off >= 1; off >>= 1) v += __shfl_xor(v, off, 64);
        if (ln == 0) dout[0] = -v * (1.0f / (float)Bsz);
    }
}

extern "C" void kernel_launch(void* const* d_in, const int* in_sizes, int n_in,
                              void* d_out, int out_size, void* d_ws, size_t ws_size,
                              hipStream_t stream) {
    const float* enc    = (const float*)d_in[0];
    const int*   labels = (const int*)d_in[1];
    const int*   mask   = (const int*)d_in[2];
    const int*   lengths= (const int*)d_in[3];
    const float* fcw    = (const float*)d_in[4];
    const float* fcb    = (const float*)d_in[5];
    const float* startt = (const float*)d_in[6];
    const float* endt   = (const float*)d_in[7];
    const float* trans  = (const float*)d_in[8];

    float* out = (float*)d_out;
    float* em  = (float*)d_ws;                                // 294912 f
    float* R2  = em + (size_t)Bsz * Ssz * Tsz;                // 82944 f
    float* MV  = R2 + (size_t)Bsz * NCH * 81;                 // 82944 f
    float* ll  = MV + (size_t)Bsz * NCH * 81;                 // 64 f
    int*   cnt = (int*)(ll + Bsz);                            // 1 int

    emscan2_kernel<<<Bsz * NCH, 256, 0, stream>>>(enc, fcw, fcb, mask, trans,
                                                  em, R2, MV, cnt);
    vit3_kernel<<<Bsz, 192, 0, stream>>>(em, labels, mask, lengths, startt, endt,
                                         trans, R2, MV, out + 1, ll, out, cnt);
}

// Round 11
// 69.006 us; speedup vs baseline: 1.0293x; 1.0293x over previous
//
#include <hip/hip_runtime.h>

#define Bsz 64
#define Ssz 512
#define Hsz 768
#define Tsz 9
#define NCH 16
#define LOG2E 1.4426950408889634f
#define LN2F  0.6931471805599453f

__device__ __forceinline__ int SK(int s) { return s * Tsz + ((s >> 5) << 1); }

#define FMA4(ACC, V, W)                                                    \
    ACC = fmaf((V).x, (W).x, fmaf((V).y, (W).y,                            \
          fmaf((V).z, (W).z, fmaf((V).w, (W).w, (ACC)))))

// ============ K1: fused emissions GEMM (reg-pipelined) + in-block scans ============
// grid = B*NCH = 1024 blocks x 256 threads. Block (b,c) covers rows [c*32,c*32+32).
// Phase G: 2 positions/thread-group, x-loads double-buffered in NAMED registers
// (>=4 loads always in flight -> MLP restored; r10's VGPR=52 serial-latency fix).
// Phase G2: row 32 recomputed bit-identically to block c+1's row 0.
// Phase S: 18 chunk-scan tasks (col-parallel shuffles) from LDS, verbatim r10.
__global__ __launch_bounds__(256, 4) void emscan3_kernel(
    const float* __restrict__ x, const float* __restrict__ fcw,
    const float* __restrict__ fcb, const int* __restrict__ mask,
    const float* __restrict__ trans, float* __restrict__ em,
    float* __restrict__ R2, float* __restrict__ MV, int* __restrict__ cnt) {
    __shared__ __align__(16) float4 w4[Tsz * Hsz / 4];   // 27648 B
    __shared__ float bias[Tsz];
    __shared__ float em_w[33 * Tsz];
    __shared__ int   mk_w[33];
    __shared__ float Elds[81];
    __shared__ float Tlds[81];

    const int tid = threadIdx.x;
    const int bc = blockIdx.x;
    const int b = bc >> 4, c = bc & 15;
    const int base = c * 32;
    const size_t pos0 = (size_t)bc * 32;

    if (bc == 0 && tid == 0) *cnt = 0;

    const float4* fw4 = reinterpret_cast<const float4*>(fcw);
#pragma unroll
    for (int i = 0; i < 7; ++i) {
        const int o = tid + i * 256;
        if (o < 1728) w4[o] = fw4[o];
    }
    if (tid < Tsz) bias[tid] = fcb[tid];
    if (tid >= 16 && tid < 97) {
        const float t = trans[tid - 16];
        Tlds[tid - 16] = t;
        Elds[tid - 16] = exp2f(t * LOG2E);
    }
    if (tid >= 128 && tid < 161) {
        const int s = base + (tid - 128);
        mk_w[tid - 128] = (s < Ssz) ? mask[b * Ssz + s] : 0;
    }
    __syncthreads();

    const int p = tid >> 4, l = tid & 15;

    // ---- phase G: positions (pos0+p) and (pos0+16+p), reg-double-buffered ----
    {
        const float4* xr0 = reinterpret_cast<const float4*>(x + (pos0 + p) * Hsz);
        const float4* xr1 = reinterpret_cast<const float4*>(x + (pos0 + 16 + p) * Hsz);
        float acc0[Tsz], acc1[Tsz];
#pragma unroll
        for (int t = 0; t < Tsz; ++t) { acc0[t] = 0.0f; acc1[t] = 0.0f; }

        float4 A0, A1, A2, A3, B0, B1, B2, B3;
#define FMAP(V0, V1, V2, V3, I)                                            \
        _Pragma("unroll") for (int t = 0; t < Tsz; ++t) {                  \
            const float4 w0 = w4[t * 192 + (I) * 16 + l];                  \
            const float4 w1 = w4[t * 192 + ((I) + 1) * 16 + l];            \
            FMA4(acc0[t], V0, w0); FMA4(acc1[t], V1, w0);                  \
            FMA4(acc0[t], V2, w1); FMA4(acc1[t], V3, w1);                  \
        }
        A0 = xr0[0 * 16 + l];  A1 = xr1[0 * 16 + l];
        A2 = xr0[1 * 16 + l];  A3 = xr1[1 * 16 + l];
        B0 = xr0[2 * 16 + l];  B1 = xr1[2 * 16 + l];
        B2 = xr0[3 * 16 + l];  B3 = xr1[3 * 16 + l];
        FMAP(A0, A1, A2, A3, 0)
        A0 = xr0[4 * 16 + l];  A1 = xr1[4 * 16 + l];
        A2 = xr0[5 * 16 + l];  A3 = xr1[5 * 16 + l];
        FMAP(B0, B1, B2, B3, 2)
        B0 = xr0[6 * 16 + l];  B1 = xr1[6 * 16 + l];
        B2 = xr0[7 * 16 + l];  B3 = xr1[7 * 16 + l];
        FMAP(A0, A1, A2, A3, 4)
        A0 = xr0[8 * 16 + l];  A1 = xr1[8 * 16 + l];
        A2 = xr0[9 * 16 + l];  A3 = xr1[9 * 16 + l];
        FMAP(B0, B1, B2, B3, 6)
        B0 = xr0[10 * 16 + l]; B1 = xr1[10 * 16 + l];
        B2 = xr0[11 * 16 + l]; B3 = xr1[11 * 16 + l];
        FMAP(A0, A1, A2, A3, 8)
        FMAP(B0, B1, B2, B3, 10)
#undef FMAP

        // 16-lane tree reduce (xor masks 1,2,4,8 stay inside the group)
#pragma unroll
        for (int t = 0; t < Tsz; ++t) {
            acc0[t] += __shfl_xor(acc0[t], 1, 64);
            acc0[t] += __shfl_xor(acc0[t], 2, 64);
            acc0[t] += __shfl_xor(acc0[t], 4, 64);
            acc0[t] += __shfl_xor(acc0[t], 8, 64);
            acc1[t] += __shfl_xor(acc1[t], 1, 64);
            acc1[t] += __shfl_xor(acc1[t], 2, 64);
            acc1[t] += __shfl_xor(acc1[t], 4, 64);
            acc1[t] += __shfl_xor(acc1[t], 8, 64);
        }
        float o0 = 0.0f, o1 = 0.0f;
#pragma unroll
        for (int t = 0; t < Tsz; ++t)
            if (l == t) { o0 = acc0[t]; o1 = acc1[t]; }
        if (l < Tsz) {
            const float bse = bias[l];
            const float v0 = o0 + bse, v1 = o1 + bse;
            em[(pos0 + p) * Tsz + l] = v0;
            em_w[p * Tsz + l] = v0;
            em[(pos0 + 16 + p) * Tsz + l] = v1;
            em_w[(16 + p) * Tsz + l] = v1;
        }
    }

    // ---- phase G2: row 32 (bit-identical to block c+1's row-0 code path) ----
    if (c < 15 && tid < 16) {
        const float4* xr2 = reinterpret_cast<const float4*>(x + (pos0 + 32) * Hsz);
        float acc2[Tsz];
#pragma unroll
        for (int t = 0; t < Tsz; ++t) acc2[t] = 0.0f;
        float4 A0, A2, B0, B2;
#define FMAS(V0, V2, I)                                                    \
        _Pragma("unroll") for (int t = 0; t < Tsz; ++t) {                  \
            const float4 w0 = w4[t * 192 + (I) * 16 + l];                  \
            const float4 w1 = w4[t * 192 + ((I) + 1) * 16 + l];            \
            FMA4(acc2[t], V0, w0); FMA4(acc2[t], V2, w1);                  \
        }
        A0 = xr2[0 * 16 + l];  A2 = xr2[1 * 16 + l];
        B0 = xr2[2 * 16 + l];  B2 = xr2[3 * 16 + l];
        FMAS(A0, A2, 0)
        A0 = xr2[4 * 16 + l];  A2 = xr2[5 * 16 + l];
        FMAS(B0, B2, 2)
        B0 = xr2[6 * 16 + l];  B2 = xr2[7 * 16 + l];
        FMAS(A0, A2, 4)
        A0 = xr2[8 * 16 + l];  A2 = xr2[9 * 16 + l];
        FMAS(B0, B2, 6)
        B0 = xr2[10 * 16 + l]; B2 = xr2[11 * 16 + l];
        FMAS(A0, A2, 8)
        FMAS(B0, B2, 10)
#undef FMAS
#pragma unroll
        for (int t = 0; t < Tsz; ++t) {
            acc2[t] += __shfl_xor(acc2[t], 1, 64);
            acc2[t] += __shfl_xor(acc2[t], 2, 64);
            acc2[t] += __shfl_xor(acc2[t], 4, 64);
            acc2[t] += __shfl_xor(acc2[t], 8, 64);
        }
        float o2 = 0.0f;
#pragma unroll
        for (int t = 0; t < Tsz; ++t)
            if (l == t) o2 = acc2[t];
        if (l < Tsz) em_w[32 * Tsz + l] = o2 + bias[l];
    }
    __syncthreads();

    // ---- phase S: 18 scan tasks on waves 0-2 (verbatim r10) ----
    const int wv = tid >> 6, ln = tid & 63;
    const int q = ln / 9;
    const int j = ln - q * 9;
    const int tsk = wv * 7 + q;
    if (wv >= 3 || q >= 7 || tsk >= 18) return;
    const int lb = 9 * q;
    const int ns = (c == 15) ? 31 : 32;

    if (tsk < 9) {
        const int a = tsk;
        float Ecol[Tsz];
#pragma unroll
        for (int i = 0; i < Tsz; ++i) Ecol[i] = Elds[i * Tsz + j];
        float pp = (j == a) ? 1.0f : 0.0f;
        float K = 0.0f;
        for (int r = 1; r <= ns; ++r) {
            float g = __shfl(pp, lb, 64) * Ecol[0];
#pragma unroll
            for (int i = 1; i < Tsz; ++i)
                g = fmaf(__shfl(pp, lb + i, 64), Ecol[i], g);
            const float np = g * exp2f(em_w[r * Tsz + j] * LOG2E);
            if (mk_w[r] > 0) pp = np;
            if (((r - 1) & 7) == 7) {
                float ss = __shfl(pp, lb, 64);
#pragma unroll
                for (int i = 1; i < Tsz; ++i) ss += __shfl(pp, lb + i, 64);
                K += __log2f(ss);
                const float inv = 1.0f / ss;
                pp *= inv;
            }
        }
        R2[((size_t)bc * Tsz + a) * Tsz + j] = K + __log2f(pp);
    } else {
        const int a = tsk - 9;
        float Tcol[Tsz];
#pragma unroll
        for (int i = 0; i < Tsz; ++i) Tcol[i] = Tlds[i * Tsz + j];
        float pp = (j == a) ? 0.0f : -1e30f;
        for (int r = 1; r <= ns; ++r) {
            float g = __shfl(pp, lb, 64) + Tcol[0];
#pragma unroll
            for (int i = 1; i < Tsz; ++i)
                g = fmaxf(g, __shfl(pp, lb + i, 64) + Tcol[i]);
            if (mk_w[r] > 0) pp = g + em_w[r * Tsz + j];
        }
        MV[(size_t)bc * 81 + a * Tsz + j] = pp;
    }
}

// first-max argmax of 9 values (strict > keeps FIRST max)
__device__ __forceinline__ void amax9(const float (&v)[Tsz], float& bv, int& bi) {
    float w01v = (v[1] > v[0]) ? v[1] : v[0]; int w01i = (v[1] > v[0]) ? 1 : 0;
    float w23v = (v[3] > v[2]) ? v[3] : v[2]; int w23i = (v[3] > v[2]) ? 3 : 2;
    float w45v = (v[5] > v[4]) ? v[5] : v[4]; int w45i = (v[5] > v[4]) ? 5 : 4;
    float w67v = (v[7] > v[6]) ? v[7] : v[6]; int w67i = (v[7] > v[6]) ? 7 : 6;
    float x03v = (w23v > w01v) ? w23v : w01v; int x03i = (w23v > w01v) ? w23i : w01i;
    float x47v = (w67v > w45v) ? w67v : w45v; int x47i = (w67v > w45v) ? w67i : w45i;
    float y07v = (x47v > x03v) ? x47v : x03v; int y07i = (x47v > x03v) ? x47i : x03i;
    bv = (v[8] > y07v) ? v[8] : y07v;
    bi = (v[8] > y07v) ? 8 : y07i;
}

// ============ K2: per-batch finish + fused final reduce (verbatim r10) ============
__global__ __launch_bounds__(192, 1) void vit3_kernel(
    const float* __restrict__ em, const int* __restrict__ labels,
    const int* __restrict__ mask, const int* __restrict__ lengths,
    const float* __restrict__ start_t, const float* __restrict__ end_t,
    const float* __restrict__ trans, const float* __restrict__ R2,
    const float* __restrict__ MV, float* __restrict__ out_path,
    float* __restrict__ ll, float* __restrict__ dout, int* __restrict__ cnt) {
    __shared__ __align__(16) float em_s[4640];          // skewed [s][j]
    __shared__ __align__(16) int   mk_s[Ssz];
    __shared__ __align__(16) float mv_s[NCH * 81];
    __shared__ __align__(16) float r2_s[NCH * 81];
    __shared__ float tr_s[81];
    __shared__ float st_s[12], en_s[12];
    __shared__ __align__(16) float alc[2][NCH][12];
    __shared__ float a2c[2][12];
    __shared__ unsigned char bp[(Ssz - 1) * Tsz];
    __shared__ unsigned char mapA[64][12], mapB[64][12];
    __shared__ float den_sh, num_sh;
    __shared__ int lastf;

    const int b = blockIdx.x, tid = threadIdx.x;
    const int wv = tid >> 6, ln = tid & 63;
    const int c = tid / 12, j9 = tid % 12;
    const float* emb = em + (size_t)b * Ssz * Tsz;
    const int* mkb = mask + b * Ssz;
    const int* lbb = labels + b * Ssz;

    for (int i = tid; i < Ssz * Tsz; i += 192) {
        const int s = i / 9, j = i - s * 9;
        em_s[SK(s) + j] = emb[i];
    }
    for (int i = tid; i < Ssz; i += 192) mk_s[i] = mkb[i];
    {
        const float4* v4 = reinterpret_cast<const float4*>(MV + (size_t)b * NCH * 81);
        float4* vd = reinterpret_cast<float4*>(mv_s);
        for (int i = tid; i < NCH * 81 / 4; i += 192) vd[i] = v4[i];
        const float4* r4 = reinterpret_cast<const float4*>(R2 + (size_t)b * NCH * 81);
        float4* rd = reinterpret_cast<float4*>(r2_s);
        for (int i = tid; i < NCH * 81 / 4; i += 192) rd[i] = r4[i];
        if (tid < 81) tr_s[tid] = trans[tid];
        if (tid >= 96 && tid < 96 + Tsz) {
            st_s[tid - 96] = start_t[tid - 96];
            en_s[tid - 96] = end_t[tid - 96];
        }
    }
    __syncthreads();

    float tc[Tsz];
    const int jj = (j9 < Tsz) ? j9 : Tsz - 1;
#pragma unroll
    for (int i = 0; i < Tsz; ++i) tc[i] = tr_s[i * Tsz + jj];

    float aj = 0.0f;
    if (c == 0 && j9 < Tsz) {
        aj = st_s[j9] + em_s[j9];
        alc[0][0][j9] = aj;
    }
    if (wv == 1 && ln < Tsz) a2c[0][ln] = (st_s[ln] + em_s[ln]) * LOG2E;

    for (int r = 0; r < NCH; ++r) {
        __syncthreads();
        if (r < NCH - 1 && c == r + 1 && j9 < Tsz) {
            const float* M = &mv_s[r * 81];
            float m = alc[0][r][0] + M[j9];
#pragma unroll
            for (int i = 1; i < Tsz; ++i)
                m = fmaxf(m, alc[0][r][i] + M[i * Tsz + j9]);
            aj = m;
            alc[0][c][j9] = m;
        }
        if (wv == 1 && ln < Tsz) {
            const float* Rr = &r2_s[r * 81];
            float xi[Tsz];
#pragma unroll
            for (int i = 0; i < Tsz; ++i) xi[i] = a2c[r & 1][i] + Rr[i * Tsz + ln];
            float m = xi[0];
#pragma unroll
            for (int i = 1; i < Tsz; ++i) m = fmaxf(m, xi[i]);
            float sm = 0.0f;
#pragma unroll
            for (int i = 0; i < Tsz; ++i) sm += exp2f(xi[i] - m);
            a2c[(r + 1) & 1][ln] = m + __log2f(sm);
        }
    }

    int pb = 0;
    for (int k = 0; k < 32; ++k) {
        __syncthreads();
        const int s = c * 32 + 1 + k;
        if (j9 < Tsz && s <= Ssz - 1) {
            const int mk = mk_s[s];
            float av[12];
            const float4* ap = reinterpret_cast<const float4*>(&alc[pb][c][0]);
            *reinterpret_cast<float4*>(&av[0]) = ap[0];
            *reinterpret_cast<float4*>(&av[4]) = ap[1];
            *reinterpret_cast<float4*>(&av[8]) = ap[2];
            float v[Tsz];
#pragma unroll
            for (int i = 0; i < Tsz; ++i) v[i] = av[i] + tc[i];
            float bv; int bi;
            amax9(v, bv, bi);
            bp[(s - 1) * Tsz + j9] = (unsigned char)((mk > 0) ? bi : j9);
            if (mk > 0) aj = bv + em_s[SK(s) + j9];
        }
        if (j9 < Tsz) alc[1 - pb][c][j9] = aj;
        pb ^= 1;
    }
    __syncthreads();

    float bb = alc[0][NCH - 1][0] + en_s[0];
    int last = 0;
#pragma unroll
    for (int q = 1; q < Tsz; ++q) {
        const float qq = alc[0][NCH - 1][q] + en_s[q];
        if (qq > bb) { bb = qq; last = q; }
    }

    const int lo = ln * 8;
    const int hi = min(lo + 7, Ssz - 2);
    if (wv == 0) {
        int xf[Tsz];
#pragma unroll
        for (int t = 0; t < Tsz; ++t) xf[t] = t;
        for (int k = hi; k >= lo; --k) {
#pragma unroll
            for (int t = 0; t < Tsz; ++t) xf[t] = bp[k * Tsz + xf[t]];
        }
#pragma unroll
        for (int t = 0; t < Tsz; ++t) mapA[ln][t] = (unsigned char)xf[t];
    } else if (wv == 1) {
        if (ln == 0) {
            float xv[Tsz];
#pragma unroll
            for (int i = 0; i < Tsz; ++i) xv[i] = a2c[0][i] + en_s[i] * LOG2E;
            float m = xv[0];
#pragma unroll
            for (int i = 1; i < Tsz; ++i) m = fmaxf(m, xv[i]);
            float sm = 0.0f;
#pragma unroll
            for (int i = 0; i < Tsz; ++i) sm += exp2f(xv[i] - m);
            den_sh = m + __log2f(sm);
        }
    } else {
        float part = 0.0f;
        for (int s = 1 + ln; s < Ssz; s += 64) {
            if (mk_s[s] > 0) {
                const int tg = lbb[s];
                int pq = s - 1;
                while (pq > 0 && mk_s[pq] == 0) --pq;
                part += tr_s[lbb[pq] * Tsz + tg] + em_s[SK(s) + tg];
            }
        }
#pragma unroll
        for (int off = 32; off >= 1; off >>= 1) part += __shfl_xor(part, off, 64);
        if (ln == 0) {
            const int tg0 = lbb[0];
            float num = part + st_s[tg0] + em_s[tg0];
            int pq = Ssz - 1;
            while (pq > 0 && mk_s[pq] == 0) --pq;
            num += en_s[lbb[pq]];
            num_sh = num;
        }
    }

#define VIT_RND(CUR, NXT, D)                                               \
    {                                                                      \
        unsigned char nn[Tsz];                                             \
        if (wv == 0) {                                                     \
            const int o = ln + (D);                                        \
            if (o < 64) {                                                  \
                _Pragma("unroll") for (int t = 0; t < Tsz; ++t)            \
                    nn[t] = CUR[ln][CUR[o][t]];                            \
            } else {                                                       \
                _Pragma("unroll") for (int t = 0; t < Tsz; ++t)            \
                    nn[t] = CUR[ln][t];                                    \
            }                                                              \
        }                                                                  \
        __syncthreads();                                                   \
        if (wv == 0) {                                                     \
            _Pragma("unroll") for (int t = 0; t < Tsz; ++t)                \
                NXT[ln][t] = nn[t];                                        \
        }                                                                  \
        __syncthreads();                                                   \
    }
    VIT_RND(mapA, mapB, 1)
    VIT_RND(mapB, mapA, 2)
    VIT_RND(mapA, mapB, 4)
    VIT_RND(mapB, mapA, 8)
    VIT_RND(mapA, mapB, 16)
    VIT_RND(mapB, mapA, 32)
#undef VIT_RND

    if (wv == 0) {
        int t = (ln == 63) ? last : (int)mapA[ln + 1][last];
        float* op = out_path + (size_t)b * Ssz;
        for (int k = hi; k >= lo; --k) {
            t = bp[k * Tsz + t];
            op[k] = (float)t;
        }
        if (ln == 0) op[Ssz - 1] = (float)last;
    }
    if (b == 0 && wv == 2) dout[1 + Bsz * Ssz + ln] = (float)lengths[ln];

    if (tid == 0) {
        ll[b] = num_sh - den_sh * LN2F;
        __threadfence();
        lastf = (atomicAdd(cnt, 1) == Bsz - 1) ? 1 : 0;
    }
    __syncthreads();
    if (lastf && wv == 0) {
        __threadfence();
        float v = ll[ln];
#pragma unroll
        for (int off = 32; off >= 1; off >>= 1) v += __shfl_xor(v, off, 64);
        if (ln == 0) dout[0] = -v * (1.0f / (float)Bsz);
    }
}

extern "C" void kernel_launch(void* const* d_in, const int* in_sizes, int n_in,
                              void* d_out, int out_size, void* d_ws, size_t ws_size,
                              hipStream_t stream) {
    const float* enc    = (const float*)d_in[0];
    const int*   labels = (const int*)d_in[1];
    const int*   mask   = (const int*)d_in[2];
    const int*   lengths= (const int*)d_in[3];
    const float* fcw    = (const float*)d_in[4];
    const float* fcb    = (const float*)d_in[5];
    const float* startt = (const float*)d_in[6];
    const float* endt   = (const float*)d_in[7];
    const float* trans  = (const float*)d_in[8];

    float* out = (float*)d_out;
    float* em  = (float*)d_ws;                                // 294912 f
    float* R2  = em + (size_t)Bsz * Ssz * Tsz;                // 82944 f
    float* MV  = R2 + (size_t)Bsz * NCH * 81;                 // 82944 f
    float* ll  = MV + (size_t)Bsz * NCH * 81;                 // 64 f
    int*   cnt = (int*)(ll + Bsz);                            // 1 int

    emscan3_kernel<<<Bsz * NCH, 256, 0, stream>>>(enc, fcw, fcb, mask, trans,
                                                  em, R2, MV, cnt);
    vit3_kernel<<<Bsz, 192, 0, stream>>>(em, labels, mask, lengths, startt, endt,
                                         trans, R2, MV, out + 1, ll, out, cnt);
}

// Round 12
// 68.365 us; speedup vs baseline: 1.0390x; 1.0094x over previous
//
#include <hip/hip_runtime.h>

#define Bsz 64
#define Ssz 512
#define Hsz 768
#define Tsz 9
#define NCH 16
#define LOG2E 1.4426950408889634f
#define LN2F  0.6931471805599453f
#define PSTR 17

__device__ __forceinline__ int SK(int s) { return s * Tsz + ((s >> 5) << 1); }

// ---------------- K1: emissions = enc @ fc_w^T + fc_b ----------------
// r2/r4 geometry (empirically fastest: ~28us): 2048 blocks x 256 threads,
// 16 positions/block, 16 lanes/position, 12 independent x-loads/thread,
// 4 blocks/CU resident. PSTR=17 kills the old 32-way read-phase conflict.
__global__ __launch_bounds__(256) void emis_kernel(
    const float* __restrict__ x, const float* __restrict__ fcw,
    const float* __restrict__ fcb, float* __restrict__ em,
    int* __restrict__ cnt) {
    __shared__ __align__(16) float4 w4[Tsz * Hsz / 4];   // 27648 B
    __shared__ float bias[Tsz];
    __shared__ float part[16 * Tsz * PSTR];              // 9792 B
    const int tid = threadIdx.x;
    if (blockIdx.x == 0 && tid == 0) *cnt = 0;           // vit3's reduce counter
    const float4* fw4 = reinterpret_cast<const float4*>(fcw);
#pragma unroll
    for (int i = 0; i < 7; ++i) {
        const int o = tid + i * 256;
        if (o < 1728) w4[o] = fw4[o];
    }
    if (tid < Tsz) bias[tid] = fcb[tid];
    __syncthreads();

    const int p = tid >> 4, l = tid & 15;
    const float4* xr = reinterpret_cast<const float4*>(
        x + ((size_t)blockIdx.x * 16 + p) * Hsz);
    float acc[Tsz];
#pragma unroll
    for (int t = 0; t < Tsz; ++t) acc[t] = 0.0f;
#pragma unroll
    for (int i = 0; i < 12; ++i) {
        const float4 xv = xr[i * 16 + l];
#pragma unroll
        for (int t = 0; t < Tsz; ++t) {
            const float4 wv = w4[t * 192 + i * 16 + l];
            acc[t] = fmaf(xv.x, wv.x, fmaf(xv.y, wv.y,
                     fmaf(xv.z, wv.z, fmaf(xv.w, wv.w, acc[t]))));
        }
    }
#pragma unroll
    for (int t = 0; t < Tsz; ++t) part[(p * Tsz + t) * PSTR + l] = acc[t];
    __syncthreads();
    if (tid < 16 * Tsz) {
        const int pq = tid / Tsz, t = tid - pq * Tsz;
        float s = bias[t];
#pragma unroll
        for (int l2 = 0; l2 < 16; ++l2) s += part[(pq * Tsz + t) * PSTR + l2];
        em[(size_t)blockIdx.x * (16 * Tsz) + tid] = s;
    }
}

// ---------------- K2: chunk transfer matrices, column-parallel (r8 verbatim) ---
// Row-task rho = (bc2, a): 9 lanes, lane j holds scalar pp = M[a][j] and the
// 9-float transition COLUMN j in regs. Step = 9 shfl + 9 fma/fmax.
__global__ __launch_bounds__(256, 1) void scan_kernel(
    const float* __restrict__ em, const int* __restrict__ mask,
    const float* __restrict__ trans, float* __restrict__ R2,
    float* __restrict__ MV) {
    __shared__ float Tlds[81];
    __shared__ float Elds[81];
    const int tid = threadIdx.x;
    if (tid < 81) {
        const float t = trans[tid];
        Tlds[tid] = t;
        Elds[tid] = exp2f(t * LOG2E);
    }
    __syncthreads();

    const int wid = tid >> 6, ln = tid & 63;
    const int q = ln / 9;                    // 0..7 (q==7 -> idle lane 63)
    const int j = ln - q * 9;
    const int W = blockIdx.x * 4 + wid;
    const int rho = W * 7 + q;               // row-task id
    if (q >= 7 || rho >= 2048 * Tsz) return;

    const int a = rho % Tsz;
    const int bc2 = rho / Tsz;               // 0..2047
    const bool isLSE = bc2 < 1024;
    const int bc = isLSE ? bc2 : bc2 - 1024;
    const int b = bc >> 4, c = bc & 15;
    const int lb = 9 * q;                    // group base lane in wave

    const float* emb = em + (size_t)b * Ssz * Tsz;
    const int* mkb = mask + b * Ssz;
    const int s_lo = c * 32 + 1;
    const int s_hi = min(c * 32 + 32, Ssz - 1);

    float ec = emb[s_lo * Tsz + j];
    int mc = mkb[s_lo];

    if (isLSE) {
        float Ecol[Tsz];
#pragma unroll
        for (int i = 0; i < Tsz; ++i) Ecol[i] = Elds[i * Tsz + j];
        float pp = (j == a) ? 1.0f : 0.0f;
        float K = 0.0f;
        for (int s = s_lo; s <= s_hi; ++s) {
            const int sp = (s < s_hi) ? s + 1 : s;
            const float en = emb[sp * Tsz + j];
            const int mn = mkb[sp];
            float g = __shfl(pp, lb, 64) * Ecol[0];
#pragma unroll
            for (int i = 1; i < Tsz; ++i)
                g = fmaf(__shfl(pp, lb + i, 64), Ecol[i], g);
            const float np = g * exp2f(ec * LOG2E);
            if (mc > 0) pp = np;
            if (((s - s_lo) & 7) == 7) {
                float ss = __shfl(pp, lb, 64);
#pragma unroll
                for (int i = 1; i < Tsz; ++i) ss += __shfl(pp, lb + i, 64);
                K += __log2f(ss);
                const float inv = 1.0f / ss;
                pp *= inv;
            }
            ec = en; mc = mn;
        }
        R2[((size_t)bc * Tsz + a) * Tsz + j] = K + __log2f(pp);
    } else {
        float Tcol[Tsz];
#pragma unroll
        for (int i = 0; i < Tsz; ++i) Tcol[i] = Tlds[i * Tsz + j];
        float pp = (j == a) ? 0.0f : -1e30f;
        for (int s = s_lo; s <= s_hi; ++s) {
            const int sp = (s < s_hi) ? s + 1 : s;
            const float en = emb[sp * Tsz + j];
            const int mn = mkb[sp];
            float g = __shfl(pp, lb, 64) + Tcol[0];
#pragma unroll
            for (int i = 1; i < Tsz; ++i)
                g = fmaxf(g, __shfl(pp, lb + i, 64) + Tcol[i]);
            if (mc > 0) pp = g + ec;
            ec = en; mc = mn;
        }
        MV[(size_t)bc * 81 + a * Tsz + j] = pp;
    }
}

// first-max argmax of 9 values (strict > keeps FIRST max)
__device__ __forceinline__ void amax9(const float (&v)[Tsz], float& bv, int& bi) {
    float w01v = (v[1] > v[0]) ? v[1] : v[0]; int w01i = (v[1] > v[0]) ? 1 : 0;
    float w23v = (v[3] > v[2]) ? v[3] : v[2]; int w23i = (v[3] > v[2]) ? 3 : 2;
    float w45v = (v[5] > v[4]) ? v[5] : v[4]; int w45i = (v[5] > v[4]) ? 5 : 4;
    float w67v = (v[7] > v[6]) ? v[7] : v[6]; int w67i = (v[7] > v[6]) ? 7 : 6;
    float x03v = (w23v > w01v) ? w23v : w01v; int x03i = (w23v > w01v) ? w23i : w01i;
    float x47v = (w67v > w45v) ? w67v : w45v; int x47i = (w67v > w45v) ? w67i : w45i;
    float y07v = (x47v > x03v) ? x47v : x03v; int y07i = (x47v > x03v) ? x47i : x03i;
    bv = (v[8] > y07v) ? v[8] : y07v;
    bi = (v[8] > y07v) ? 8 : y07i;
}

// ============ K3: per-batch finish + fused final reduce (r10 verbatim) ============
__global__ __launch_bounds__(192, 1) void vit3_kernel(
    const float* __restrict__ em, const int* __restrict__ labels,
    const int* __restrict__ mask, const int* __restrict__ lengths,
    const float* __restrict__ start_t, const float* __restrict__ end_t,
    const float* __restrict__ trans, const float* __restrict__ R2,
    const float* __restrict__ MV, float* __restrict__ out_path,
    float* __restrict__ ll, float* __restrict__ dout, int* __restrict__ cnt) {
    __shared__ __align__(16) float em_s[4640];          // skewed [s][j]
    __shared__ __align__(16) int   mk_s[Ssz];
    __shared__ __align__(16) float mv_s[NCH * 81];
    __shared__ __align__(16) float r2_s[NCH * 81];
    __shared__ float tr_s[81];
    __shared__ float st_s[12], en_s[12];
    __shared__ __align__(16) float alc[2][NCH][12];
    __shared__ float a2c[2][12];
    __shared__ unsigned char bp[(Ssz - 1) * Tsz];
    __shared__ unsigned char mapA[64][12], mapB[64][12];
    __shared__ float den_sh, num_sh;
    __shared__ int lastf;

    const int b = blockIdx.x, tid = threadIdx.x;
    const int wv = tid >> 6, ln = tid & 63;
    const int c = tid / 12, j9 = tid % 12;
    const float* emb = em + (size_t)b * Ssz * Tsz;
    const int* mkb = mask + b * Ssz;
    const int* lbb = labels + b * Ssz;

    for (int i = tid; i < Ssz * Tsz; i += 192) {
        const int s = i / 9, j = i - s * 9;
        em_s[SK(s) + j] = emb[i];
    }
    for (int i = tid; i < Ssz; i += 192) mk_s[i] = mkb[i];
    {
        const float4* v4 = reinterpret_cast<const float4*>(MV + (size_t)b * NCH * 81);
        float4* vd = reinterpret_cast<float4*>(mv_s);
        for (int i = tid; i < NCH * 81 / 4; i += 192) vd[i] = v4[i];
        const float4* r4 = reinterpret_cast<const float4*>(R2 + (size_t)b * NCH * 81);
        float4* rd = reinterpret_cast<float4*>(r2_s);
        for (int i = tid; i < NCH * 81 / 4; i += 192) rd[i] = r4[i];
        if (tid < 81) tr_s[tid] = trans[tid];
        if (tid >= 96 && tid < 96 + Tsz) {
            st_s[tid - 96] = start_t[tid - 96];
            en_s[tid - 96] = end_t[tid - 96];
        }
    }
    __syncthreads();

    float tc[Tsz];
    const int jj = (j9 < Tsz) ? j9 : Tsz - 1;
#pragma unroll
    for (int i = 0; i < Tsz; ++i) tc[i] = tr_s[i * Tsz + jj];

    float aj = 0.0f;
    if (c == 0 && j9 < Tsz) {
        aj = st_s[j9] + em_s[j9];
        alc[0][0][j9] = aj;
    }
    if (wv == 1 && ln < Tsz) a2c[0][ln] = (st_s[ln] + em_s[ln]) * LOG2E;

    for (int r = 0; r < NCH; ++r) {
        __syncthreads();
        if (r < NCH - 1 && c == r + 1 && j9 < Tsz) {
            const float* M = &mv_s[r * 81];
            float m = alc[0][r][0] + M[j9];
#pragma unroll
            for (int i = 1; i < Tsz; ++i)
                m = fmaxf(m, alc[0][r][i] + M[i * Tsz + j9]);
            aj = m;
            alc[0][c][j9] = m;
        }
        if (wv == 1 && ln < Tsz) {
            const float* Rr = &r2_s[r * 81];
            float xi[Tsz];
#pragma unroll
            for (int i = 0; i < Tsz; ++i) xi[i] = a2c[r & 1][i] + Rr[i * Tsz + ln];
            float m = xi[0];
#pragma unroll
            for (int i = 1; i < Tsz; ++i) m = fmaxf(m, xi[i]);
            float sm = 0.0f;
#pragma unroll
            for (int i = 0; i < Tsz; ++i) sm += exp2f(xi[i] - m);
            a2c[(r + 1) & 1][ln] = m + __log2f(sm);
        }
    }

    int pb = 0;
    for (int k = 0; k < 32; ++k) {
        __syncthreads();
        const int s = c * 32 + 1 + k;
        if (j9 < Tsz && s <= Ssz - 1) {
            const int mk = mk_s[s];
            float av[12];
            const float4* ap = reinterpret_cast<const float4*>(&alc[pb][c][0]);
            *reinterpret_cast<float4*>(&av[0]) = ap[0];
            *reinterpret_cast<float4*>(&av[4]) = ap[1];
            *reinterpret_cast<float4*>(&av[8]) = ap[2];
            float v[Tsz];
#pragma unroll
            for (int i = 0; i < Tsz; ++i) v[i] = av[i] + tc[i];
            float bv; int bi;
            amax9(v, bv, bi);
            bp[(s - 1) * Tsz + j9] = (unsigned char)((mk > 0) ? bi : j9);
            if (mk > 0) aj = bv + em_s[SK(s) + j9];
        }
        if (j9 < Tsz) alc[1 - pb][c][j9] = aj;
        pb ^= 1;
    }
    __syncthreads();

    float bb = alc[0][NCH - 1][0] + en_s[0];
    int last = 0;
#pragma unroll
    for (int q = 1; q < Tsz; ++q) {
        const float qq = alc[0][NCH - 1][q] + en_s[q];
        if (qq > bb) { bb = qq; last = q; }
    }

    const int lo = ln * 8;
    const int hi = min(lo + 7, Ssz - 2);
    if (wv == 0) {
        int xf[Tsz];
#pragma unroll
        for (int t = 0; t < Tsz; ++t) xf[t] = t;
        for (int k = hi; k >= lo; --k) {
#pragma unroll
            for (int t = 0; t < Tsz; ++t) xf[t] = bp[k * Tsz + xf[t]];
        }
#pragma unroll
        for (int t = 0; t < Tsz; ++t) mapA[ln][t] = (unsigned char)xf[t];
    } else if (wv == 1) {
        if (ln == 0) {
            float xv[Tsz];
#pragma unroll
            for (int i = 0; i < Tsz; ++i) xv[i] = a2c[0][i] + en_s[i] * LOG2E;
            float m = xv[0];
#pragma unroll
            for (int i = 1; i < Tsz; ++i) m = fmaxf(m, xv[i]);
            float sm = 0.0f;
#pragma unroll
            for (int i = 0; i < Tsz; ++i) sm += exp2f(xv[i] - m);
            den_sh = m + __log2f(sm);
        }
    } else {
        float part = 0.0f;
        for (int s = 1 + ln; s < Ssz; s += 64) {
            if (mk_s[s] > 0) {
                const int tg = lbb[s];
                int pq = s - 1;
                while (pq > 0 && mk_s[pq] == 0) --pq;
                part += tr_s[lbb[pq] * Tsz + tg] + em_s[SK(s) + tg];
            }
        }
#pragma unroll
        for (int off = 32; off >= 1; off >>= 1) part += __shfl_xor(part, off, 64);
        if (ln == 0) {
            const int tg0 = lbb[0];
            float num = part + st_s[tg0] + em_s[tg0];
            int pq = Ssz - 1;
            while (pq > 0 && mk_s[pq] == 0) --pq;
            num += en_s[lbb[pq]];
            num_sh = num;
        }
    }

#define VIT_RND(CUR, NXT, D)                                               \
    {                                                                      \
        unsigned char nn[Tsz];                                             \
        if (wv == 0) {                                                     \
            const int o = ln + (D);                                        \
            if (o < 64) {                                                  \
                _Pragma("unroll") for (int t = 0; t < Tsz; ++t)            \
                    nn[t] = CUR[ln][CUR[o][t]];                            \
            } else {                                                       \
                _Pragma("unroll") for (int t = 0; t < Tsz; ++t)            \
                    nn[t] = CUR[ln][t];                                    \
            }                                                              \
        }                                                                  \
        __syncthreads();                                                   \
        if (wv == 0) {                                                     \
            _Pragma("unroll") for (int t = 0; t < Tsz; ++t)                \
                NXT[ln][t] = nn[t];                                        \
        }                                                                  \
        __syncthreads();                                                   \
    }
    VIT_RND(mapA, mapB, 1)
    VIT_RND(mapB, mapA, 2)
    VIT_RND(mapA, mapB, 4)
    VIT_RND(mapB, mapA, 8)
    VIT_RND(mapA, mapB, 16)
    VIT_RND(mapB, mapA, 32)
#undef VIT_RND

    if (wv == 0) {
        int t = (ln == 63) ? last : (int)mapA[ln + 1][last];
        float* op = out_path + (size_t)b * Ssz;
        for (int k = hi; k >= lo; --k) {
            t = bp[k * Tsz + t];
            op[k] = (float)t;
        }
        if (ln == 0) op[Ssz - 1] = (float)last;
    }
    if (b == 0 && wv == 2) dout[1 + Bsz * Ssz + ln] = (float)lengths[ln];

    if (tid == 0) {
        ll[b] = num_sh - den_sh * LN2F;
        __threadfence();
        lastf = (atomicAdd(cnt, 1) == Bsz - 1) ? 1 : 0;
    }
    __syncthreads();
    if (lastf && wv == 0) {
        __threadfence();
        float v = ll[ln];
#pragma unroll
        for (int off = 32; off >= 1; off >>= 1) v += __shfl_xor(v, off, 64);
        if (ln == 0) dout[0] = -v * (1.0f / (float)Bsz);
    }
}

extern "C" void kernel_launch(void* const* d_in, const int* in_sizes, int n_in,
                              void* d_out, int out_size, void* d_ws, size_t ws_size,
                              hipStream_t stream) {
    const float* enc    = (const float*)d_in[0];
    const int*   labels = (const int*)d_in[1];
    const int*   mask   = (const int*)d_in[2];
    const int*   lengths= (const int*)d_in[3];
    const float* fcw    = (const float*)d_in[4];
    const float* fcb    = (const float*)d_in[5];
    const float* startt = (const float*)d_in[6];
    const float* endt   = (const float*)d_in[7];
    const float* trans  = (const float*)d_in[8];

    float* out = (float*)d_out;
    float* em  = (float*)d_ws;                                // 294912 f
    float* R2  = em + (size_t)Bsz * Ssz * Tsz;                // 82944 f
    float* MV  = R2 + (size_t)Bsz * NCH * 81;                 // 82944 f
    float* ll  = MV + (size_t)Bsz * NCH * 81;                 // 64 f
    int*   cnt = (int*)(ll + Bsz);                            // 1 int

    emis_kernel<<<Bsz * Ssz / 16, 256, 0, stream>>>(enc, fcw, fcb, em, cnt);
    const int row_tasks = 2 * Bsz * NCH * Tsz;                // 18432
    scan_kernel<<<(row_tasks + 27) / 28, 256, 0, stream>>>(em, mask, trans, R2, MV);
    vit3_kernel<<<Bsz, 192, 0, stream>>>(em, labels, mask, lengths, startt, endt,
                                         trans, R2, MV, out + 1, ll, out, cnt);
}